// Round 1
// baseline (261.888 us; speedup 1.0000x reference)
//
#include <hip/hip_runtime.h>
#include <math.h>

namespace {
constexpr int Bn = 4, Rn = 16384, Sn = 128;
constexpr int NRAY = Bn * Rn;          // 65536 rays
constexpr int SI   = Sn - 1;           // 127 intervals
// Output layout: tuple concatenated flat in return order
constexpr size_t OFF_RGB   = 0;                                  // [B,R,3]
constexpr size_t OFF_DEPTH = OFF_RGB   + (size_t)NRAY * 3;       // [B,R,1]
constexpr size_t OFF_W     = OFF_DEPTH + (size_t)NRAY;           // [B,R,SI,1]
constexpr size_t OFF_WALL  = OFF_W     + (size_t)NRAY * SI;      // [B,R,SI,1]
constexpr size_t OFF_ALPHA = OFF_WALL  + (size_t)NRAY * SI;      // [B,R,SI,1]
constexpr size_t OFF_DMID  = OFF_ALPHA + (size_t)NRAY * SI;      // [B,R,SI,1]
constexpr float  EPSF      = 1e-10f;
}

// One wave (64 lanes) per ray; lane i owns intervals 2i and 2i+1.
__global__ __launch_bounds__(256) void raymarch_kernel(
    const float* __restrict__ colors,
    const float* __restrict__ dlog,
    const float* __restrict__ depths,
    float* __restrict__ out)
{
    const int gtid = blockIdx.x * 256 + threadIdx.x;
    const int ray  = gtid >> 6;
    const int lane = threadIdx.x & 63;

    // Per-ray data is contiguous: depths/density 128 floats, colors 384 floats.
    const float2* dp = reinterpret_cast<const float2*>(depths) + (size_t)ray * (Sn / 2);
    const float2* gp = reinterpret_cast<const float2*>(dlog)   + (size_t)ray * (Sn / 2);
    const float2* cp = reinterpret_cast<const float2*>(colors) + (size_t)ray * (Sn * 3 / 2);

    float2 d  = dp[lane];        // samples 2i, 2i+1 depths
    float2 g  = gp[lane];        // density logits
    float2 c0 = cp[lane * 3 + 0];  // colors: floats 6i..6i+5 = samples 2i, 2i+1
    float2 c1 = cp[lane * 3 + 1];
    float2 c2 = cp[lane * 3 + 2];

    // sample 2i+2 lives in lane i+1's first slots
    float d2  = __shfl_down(d.x, 1);
    float g2  = __shfl_down(g.x, 1);
    float cnx = __shfl_down(c0.x, 1);
    float cny = __shfl_down(c0.y, 1);
    float cnz = __shfl_down(c1.x, 1);

    const bool valid1 = (lane < 63);   // interval 2*63+1 = 127 does not exist

    // interval j0 = 2i : samples (2i, 2i+1)
    float delta0 = d.y - d.x;
    float dm0    = 0.5f * (d.x + d.y);
    float x0     = 0.5f * (g.x + g.y) - 1.0f;
    float cm0x   = 0.5f * (c0.x + c1.y);
    float cm0y   = 0.5f * (c0.y + c2.x);
    float cm0z   = 0.5f * (c1.x + c2.y);

    // interval j1 = 2i+1 : samples (2i+1, 2i+2) — safe values when invalid
    float delta1 = valid1 ? (d2 - d.y)            : 0.0f;
    float dm1    = valid1 ? 0.5f * (d.y + d2)     : 0.0f;
    float x1     = valid1 ? (0.5f * (g.y + g2) - 1.0f) : 0.0f;
    float cm1x   = valid1 ? 0.5f * (c1.y + cnx)   : 0.0f;
    float cm1y   = valid1 ? 0.5f * (c2.x + cny)   : 0.0f;
    float cm1z   = valid1 ? 0.5f * (c2.y + cnz)   : 0.0f;

    // softplus(x) = max(x,0) + log1p(exp(-|x|))
    float dens0 = fmaxf(x0, 0.0f) + log1pf(expf(-fabsf(x0)));
    float dens1 = fmaxf(x1, 0.0f) + log1pf(expf(-fabsf(x1)));
    float alpha0 = 1.0f - expf(-dens0 * delta0);
    float alpha1 = 1.0f - expf(-dens1 * delta1);          // == 0 for lane 63 (delta1=0)
    float t0 = 1.0f - alpha0 + EPSF;
    float t1 = valid1 ? (1.0f - alpha1 + EPSF) : 1.0f;

    // wave-wide inclusive prefix PRODUCT of p = t0*t1 (cumprod replacement)
    float s = t0 * t1;
    #pragma unroll
    for (int off = 1; off < 64; off <<= 1) {
        float y = __shfl_up(s, off);
        if (lane >= off) s *= y;
    }
    float T0 = __shfl_up(s, 1);        // exclusive scan
    if (lane == 0) T0 = 1.0f;
    float T1 = T0 * t0;

    float w0 = (alpha0 + EPSF) * T0;
    float w1 = valid1 ? (alpha1 + EPSF) * T1 : 0.0f;

    // per-interval outputs: contiguous 127-float span per ray per array
    size_t base = (size_t)ray * SI + 2 * lane;
    out[OFF_W     + base] = w0;
    out[OFF_WALL  + base] = w0;
    out[OFF_ALPHA + base] = alpha0;
    out[OFF_DMID  + base] = dm0;
    if (valid1) {
        out[OFF_W     + base + 1] = w1;
        out[OFF_WALL  + base + 1] = w1;
        out[OFF_ALPHA + base + 1] = alpha1;
        out[OFF_DMID  + base + 1] = dm1;
    }

    // composite reductions over the wave
    float wsum = w0 + w1;
    float rx = w0 * cm0x + w1 * cm1x;
    float ry = w0 * cm0y + w1 * cm1y;
    float rz = w0 * cm0z + w1 * cm1z;
    float dsum = w0 * dm0 + w1 * dm1;
    #pragma unroll
    for (int m = 32; m > 0; m >>= 1) {
        wsum += __shfl_xor(wsum, m);
        rx   += __shfl_xor(rx, m);
        ry   += __shfl_xor(ry, m);
        rz   += __shfl_xor(rz, m);
        dsum += __shfl_xor(dsum, m);
    }
    if (lane == 0) {
        float cd = dsum / (EPSF + wsum);
        if (isnan(cd)) cd = 100.0f;                 // nan_to_num(nan=MAX_DEPTH)
        cd = fminf(fmaxf(cd, 0.1f), 100.0f);        // clip(MIN_DEPTH, MAX_DEPTH); also maps ±inf
        out[OFF_RGB + (size_t)ray * 3 + 0] = rx * 2.0f - 1.0f;
        out[OFF_RGB + (size_t)ray * 3 + 1] = ry * 2.0f - 1.0f;
        out[OFF_RGB + (size_t)ray * 3 + 2] = rz * 2.0f - 1.0f;
        out[OFF_DEPTH + ray] = cd;
    }
}

extern "C" void kernel_launch(void* const* d_in, const int* in_sizes, int n_in,
                              void* d_out, int out_size, void* d_ws, size_t ws_size,
                              hipStream_t stream) {
    const float* colors = (const float*)d_in[0];
    const float* dlog   = (const float*)d_in[1];
    const float* depths = (const float*)d_in[2];
    float* out = (float*)d_out;

    dim3 grid(NRAY / 4);   // 4 waves per 256-thread block, one ray per wave
    dim3 block(256);
    hipLaunchKernelGGL(raymarch_kernel, grid, block, 0, stream, colors, dlog, depths, out);
}